// Round 18
// baseline (38.711 us; speedup 1.0000x reference)
//
#include <hip/hip_runtime.h>

// LearnableDCT as GEMM on matrix cores — 32x32x16 bf16, single fused kernel.
// EXACTLY round 14 (best: 37.0us) except stores go through L2 (no
// nontemporal) — single-variable A/B.
//
// Theory: __builtin_nontemporal_store bypasses L2 write-back, so every 256B
// wave-store hits the fabric as a partial-line burst (no aggregation into
// 2KB DRAM bursts) and completes at HBM latency (~900cy) instead of L2
// (~200cy). The fill kernel that sustains 7 TB/s writes THROUGH L2. This one
// flag explains the 37-42us plateau across five structurally different
// kernels, the R8 write-amp, and the R15 pairing sensitivity.

typedef float  f32x16 __attribute__((ext_vector_type(16)));
typedef __bf16 bf16x8 __attribute__((ext_vector_type(8)));

static __device__ __forceinline__ f32x16 mfma32(bf16x8 a, bf16x8 b, f32x16 c) {
    return __builtin_amdgcn_mfma_f32_32x32x16_bf16(a, b, c, 0, 0, 0);
}

#define MAKE_BX(va, vb, XH, XL)                                        \
    {                                                                  \
        const float vv[8] = {va.x, va.y, va.z, va.w,                   \
                             vb.x, vb.y, vb.z, vb.w};                  \
        _Pragma("unroll")                                              \
        for (int j = 0; j < 8; ++j) {                                  \
            const __bf16 hh = (__bf16)vv[j];                           \
            XH[j] = hh;                                                \
            XL[j] = (__bf16)(vv[j] - (float)hh);                       \
        }                                                              \
    }

__global__ __launch_bounds__(256) void dct_mfma(
    const float* __restrict__ x,
    const float* __restrict__ basis,
    float* __restrict__ out)
{
    __shared__ bf16x8 Alds[16 * 64];   // [F][lane], 16 KB

    const int tid  = threadIdx.x;
    const int lane = tid & 63;
    const int wv   = tid >> 6;              // 0..3
    const int T    = blockIdx.x * 4 + wv;   // wave-tile id, 0..12287
    const int wb0  = (T & 1) << 5;          // 0 or 32
    const int hb   = (T >> 1) & 63;
    const int bc   = T >> 7;                // 0..95
    const int c31  = lane & 31;
    const int half = lane >> 5;             // 0/1

    // ---- prefetch B: 8 x float4 (rows i = nc*2+half of block wb0+c31) ----
    const float* xp = x + ((size_t)bc << 18) + ((size_t)hb << 12)
                        + ((wb0 + c31) << 3);
    float4 xa[4], xb[4];
    #pragma unroll
    for (int nc = 0; nc < 4; ++nc) {
        const int i = nc * 2 + half;
        xa[nc] = *reinterpret_cast<const float4*>(xp + i * 512);
        xb[nc] = *reinterpret_cast<const float4*>(xp + i * 512 + 4);
    }

    // ---- stage hi/lo A-fragments into LDS (round-14 verified) ----
    // F=((kt*4+nc)*2+p): lane l elem j = basis[kt*32+(l&31)][nc*16+(l>>5)*8+j]
    #pragma unroll
    for (int r = 0; r < 4; ++r) {
        const int s  = tid + (r << 8);         // 0..1023
        const int F  = s >> 6;                 // wave-uniform
        const int ln = s & 63;
        const int k  = ((F >> 3) << 5) + (ln & 31);
        const int n  = (((F >> 1) & 3) << 4) + ((ln >> 5) << 3);
        const float4 v0 = *reinterpret_cast<const float4*>(basis + k * 64 + n);
        const float4 v1 = *reinterpret_cast<const float4*>(basis + k * 64 + n + 4);
        const float vv[8] = {v0.x, v0.y, v0.z, v0.w, v1.x, v1.y, v1.z, v1.w};
        bf16x8 f;
        if (F & 1) {                           // lo part
            #pragma unroll
            for (int j = 0; j < 8; ++j) {
                const __bf16 h = (__bf16)vv[j];
                f[j] = (__bf16)(vv[j] - (float)h);
            }
        } else {                               // hi part
            #pragma unroll
            for (int j = 0; j < 8; ++j)
                f[j] = (__bf16)vv[j];
        }
        Alds[s] = f;
    }
    __syncthreads();

#define ALD(F) Alds[((F) << 6) + lane]

    f32x16 acc0 = {0.f}, acc1 = {0.f};
    #pragma unroll
    for (int nc = 0; nc < 4; ++nc) {
        bf16x8 Xh, Xl;
        MAKE_BX(xa[nc], xb[nc], Xh, Xl)
        acc0 = mfma32(ALD((0 * 4 + nc) * 2 + 0), Xh, acc0);   // bh*xh (k 0..31)
        acc1 = mfma32(ALD((1 * 4 + nc) * 2 + 0), Xh, acc1);   // bh*xh (k 32..63)
        acc0 = mfma32(ALD((0 * 4 + nc) * 2 + 0), Xl, acc0);   // bh*xl
        acc1 = mfma32(ALD((1 * 4 + nc) * 2 + 0), Xl, acc1);
        acc0 = mfma32(ALD((0 * 4 + nc) * 2 + 1), Xh, acc0);   // bl*xh
        acc1 = mfma32(ALD((1 * 4 + nc) * 2 + 1), Xh, acc1);
    }

    // D: reg r -> row (r&3)+8*(r>>2)+4*half, col c31 (m74/m101-verified).
    // Plain stores: L2 write-back aggregates the 256B wave-lines into full
    // DRAM bursts; store completes at L2 latency.
    float* ob = out + ((size_t)bc << 18) + (hb << 6) + wb0 + c31;
    #pragma unroll
    for (int r = 0; r < 16; ++r) {
        const int row = (r & 3) + ((r >> 2) << 3) + (half << 2);
        ob[(size_t)row << 12]        = acc0[r];
        ob[(size_t)(row + 32) << 12] = acc1[r];
    }
}

extern "C" void kernel_launch(void* const* d_in, const int* in_sizes, int n_in,
                              void* d_out, int out_size, void* d_ws, size_t ws_size,
                              hipStream_t stream) {
    const float* x     = (const float*)d_in[0];
    const float* basis = (const float*)d_in[1];
    float* out         = (float*)d_out;

    // 12288 wave-tiles / 4 per WG = 3072 WGs, single fused kernel
    dct_mfma<<<dim3(3072), dim3(256), 0, stream>>>(x, basis, out);
}

// Round 19
// 37.143 us; speedup vs baseline: 1.0422x; 1.0422x over previous
//
#include <hip/hip_runtime.h>

// LearnableDCT as GEMM on matrix cores — 32x32x16 bf16, single fused kernel.
// This is the round-14 kernel (best measured: 37.0us), restored after the
// R18 A/B showed NT-vs-plain stores is null.
//
// Ceiling analysis (rounds 8-18): the op is a 256B-granularity transpose —
// each block's 64 outputs scatter across 64 (bc,k)-planes, so writes reach
// DRAM as ~256B bursts (one activate per 256B vs fill's 2KB => ~2.5x write
// efficiency loss; 7 TB/s fill vs our ~3.8 TB/s combined, invariant across
// six structures). Reads: ~49MB/call forced from HBM because the harness's
// 402MB fill between replays sweeps L3. Floor ~= 35us; we measure 37.
//
// Verified pieces: A/B fragment mappings + D layout (col=lane&31,
// row=(r&3)+8*(r>>2)+4*(lane>>5)) per m74/m101; hi/lo bf16 split
// (bh*xh+bh*xl+bl*xh) gives absmax 0.03125 (fp32-grade vs 0.116 threshold).

typedef float  f32x16 __attribute__((ext_vector_type(16)));
typedef __bf16 bf16x8 __attribute__((ext_vector_type(8)));

static __device__ __forceinline__ f32x16 mfma32(bf16x8 a, bf16x8 b, f32x16 c) {
    return __builtin_amdgcn_mfma_f32_32x32x16_bf16(a, b, c, 0, 0, 0);
}

#define MAKE_BX(va, vb, XH, XL)                                        \
    {                                                                  \
        const float vv[8] = {va.x, va.y, va.z, va.w,                   \
                             vb.x, vb.y, vb.z, vb.w};                  \
        _Pragma("unroll")                                              \
        for (int j = 0; j < 8; ++j) {                                  \
            const __bf16 hh = (__bf16)vv[j];                           \
            XH[j] = hh;                                                \
            XL[j] = (__bf16)(vv[j] - (float)hh);                       \
        }                                                              \
    }

__global__ __launch_bounds__(256) void dct_mfma(
    const float* __restrict__ x,
    const float* __restrict__ basis,
    float* __restrict__ out)
{
    __shared__ bf16x8 Alds[16 * 64];   // [F][lane], 16 KB

    const int tid  = threadIdx.x;
    const int lane = tid & 63;
    const int wv   = tid >> 6;              // 0..3
    const int T    = blockIdx.x * 4 + wv;   // wave-tile id, 0..12287
    const int wb0  = (T & 1) << 5;          // 0 or 32
    const int hb   = (T >> 1) & 63;
    const int bc   = T >> 7;                // 0..95
    const int c31  = lane & 31;
    const int half = lane >> 5;             // 0/1

    // ---- prefetch B: 8 x float4 (rows i = nc*2+half of block wb0+c31) ----
    // Issued first so the global-read latency hides under fragment staging.
    const float* xp = x + ((size_t)bc << 18) + ((size_t)hb << 12)
                        + ((wb0 + c31) << 3);
    float4 xa[4], xb[4];
    #pragma unroll
    for (int nc = 0; nc < 4; ++nc) {
        const int i = nc * 2 + half;
        xa[nc] = *reinterpret_cast<const float4*>(xp + i * 512);
        xb[nc] = *reinterpret_cast<const float4*>(xp + i * 512 + 4);
    }

    // ---- stage hi/lo A-fragments into LDS ----
    // F=((kt*4+nc)*2+p): lane l elem j = basis[kt*32+(l&31)][nc*16+(l>>5)*8+j]
    #pragma unroll
    for (int r = 0; r < 4; ++r) {
        const int s  = tid + (r << 8);         // 0..1023
        const int F  = s >> 6;                 // wave-uniform
        const int ln = s & 63;
        const int k  = ((F >> 3) << 5) + (ln & 31);
        const int n  = (((F >> 1) & 3) << 4) + ((ln >> 5) << 3);
        const float4 v0 = *reinterpret_cast<const float4*>(basis + k * 64 + n);
        const float4 v1 = *reinterpret_cast<const float4*>(basis + k * 64 + n + 4);
        const float vv[8] = {v0.x, v0.y, v0.z, v0.w, v1.x, v1.y, v1.z, v1.w};
        bf16x8 f;
        if (F & 1) {                           // lo part
            #pragma unroll
            for (int j = 0; j < 8; ++j) {
                const __bf16 h = (__bf16)vv[j];
                f[j] = (__bf16)(vv[j] - (float)h);
            }
        } else {                               // hi part
            #pragma unroll
            for (int j = 0; j < 8; ++j)
                f[j] = (__bf16)vv[j];
        }
        Alds[s] = f;
    }
    __syncthreads();

#define ALD(F) Alds[((F) << 6) + lane]

    f32x16 acc0 = {0.f}, acc1 = {0.f};
    #pragma unroll
    for (int nc = 0; nc < 4; ++nc) {
        bf16x8 Xh, Xl;
        MAKE_BX(xa[nc], xb[nc], Xh, Xl)
        acc0 = mfma32(ALD((0 * 4 + nc) * 2 + 0), Xh, acc0);   // bh*xh (k 0..31)
        acc1 = mfma32(ALD((1 * 4 + nc) * 2 + 0), Xh, acc1);   // bh*xh (k 32..63)
        acc0 = mfma32(ALD((0 * 4 + nc) * 2 + 0), Xl, acc0);   // bh*xl
        acc1 = mfma32(ALD((1 * 4 + nc) * 2 + 0), Xl, acc1);
        acc0 = mfma32(ALD((0 * 4 + nc) * 2 + 1), Xh, acc0);   // bl*xh
        acc1 = mfma32(ALD((1 * 4 + nc) * 2 + 1), Xh, acc1);
    }

    // D: reg r -> row (r&3)+8*(r>>2)+4*half, col c31 (m74/m101-verified).
    // Lanes 0..31 cover cols wb0..wb0+31 = full 128B line per half-wave.
    float* ob = out + ((size_t)bc << 18) + (hb << 6) + wb0 + c31;
    #pragma unroll
    for (int r = 0; r < 16; ++r) {
        const int row = (r & 3) + ((r >> 2) << 3) + (half << 2);
        __builtin_nontemporal_store(acc0[r], ob + ((size_t)row << 12));
        __builtin_nontemporal_store(acc1[r], ob + ((size_t)(row + 32) << 12));
    }
}

extern "C" void kernel_launch(void* const* d_in, const int* in_sizes, int n_in,
                              void* d_out, int out_size, void* d_ws, size_t ws_size,
                              hipStream_t stream) {
    const float* x     = (const float*)d_in[0];
    const float* basis = (const float*)d_in[1];
    float* out         = (float*)d_out;

    // 12288 wave-tiles / 4 per WG = 3072 WGs, single fused kernel
    dct_mfma<<<dim3(3072), dim3(256), 0, stream>>>(x, basis, out);
}